// Round 3
// baseline (44.352 us; speedup 1.0000x reference)
//
#include <hip/hip_runtime.h>
#include <cfloat>

#define BB    128
#define CC    4
#define NBOXN 131072
#define SPLIT 16                 // chunk-blocks per row
#define F4_PER_CHUNK 2048        // 8192 elems / 4
#define F4_PER_STRIPE 8          // float4s per thread-stripe

// ---------------- small helpers ----------------
// branchless sorted-insert into descending (a>=b>=c)
__device__ __forceinline__ void ins3(float v, float& a, float& b, float& c) {
    float m1 = fminf(a, v); a = fmaxf(a, v);
    float m2 = fminf(b, m1); b = fmaxf(b, m1);
    c = fmaxf(c, m2);
}

__device__ __forceinline__ void ins3i(float v, int i,
                                      float& a, float& b, float& c,
                                      int& ia, int& ib, int& ic) {
    if (v > c) {
        if (v > b) {
            c = b; ic = ib;
            if (v > a) { b = a; ib = ia; a = v; ia = i; }
            else       { b = v; ib = i; }
        } else { c = v; ic = i; }
    }
}

__device__ __forceinline__ float bce(float x, float t) {
    return fmaxf(x, 0.0f) - x * t + log1pf(expf(-fabsf(x)));
}

// ---------------- Kernel 1: exact per-chunk top-3 (anchor excluded) --------
// Also: anchor-owner thread stashes the positive logit; chunk-0 blocks
// prefetch the reg_preds gathers and write per-(row,ci) smooth-L1 partials.
__global__ __launch_bounds__(256) void k_chunk_top3(
        const float* __restrict__ cp,
        const float* __restrict__ rp,
        const int*   __restrict__ box_idxs,
        const float* __restrict__ rt,
        float*       __restrict__ cand,     // [BB*SPLIT*3]
        float*       __restrict__ posval,   // [BB]
        float*       __restrict__ rowreg) { // [BB*CC]
    const int row   = blockIdx.x >> 4;
    const int chunk = blockIdx.x & 15;
    const int tid   = threadIdx.x;
    const int bidx  = box_idxs[row];

    // hidden-latency gathers from reg_preds (one chunk-0 block per row)
    if (chunk == 0 && tid < CC) {
        const float pv = rp[((size_t)row * CC + tid) * NBOXN + bidx];
        const float d  = fabsf(pv - rt[row * CC + tid]);
        rowreg[row * CC + tid] = (d < 1.0f) ? 0.5f * d * d : (d - 0.5f);
    }

    const float4* src = reinterpret_cast<const float4*>(cp + (size_t)row * NBOXN)
                        + chunk * F4_PER_CHUNK;

    // pure streaming max over this thread's stripe (no per-iter checks)
    float m0 = -FLT_MAX, m1 = -FLT_MAX, m2 = -FLT_MAX, m3 = -FLT_MAX;
    #pragma unroll
    for (int k = 0; k < F4_PER_STRIPE; ++k) {
        const float4 v = src[tid + (k << 8)];
        m0 = fmaxf(m0, v.x); m1 = fmaxf(m1, v.y);
        m2 = fmaxf(m2, v.z); m3 = fmaxf(m3, v.w);
    }
    float mval = fmaxf(fmaxf(m0, m1), fmaxf(m2, m3));

    // anchor fixup: exactly one thread in the whole grid owns the anchor.
    // Re-scan its stripe with the anchor excluded (L1-hot) and stash posval.
    const int bq = bidx >> 2;  // float4 index within row
    const bool mine = (bq >= chunk * F4_PER_CHUNK) && (bq < (chunk + 1) * F4_PER_CHUNK)
                      && ((bq & 255) == tid);
    if (mine) {
        posval[row] = cp[(size_t)row * NBOXN + bidx];
        float a0 = -FLT_MAX, a1 = -FLT_MAX, a2 = -FLT_MAX, a3 = -FLT_MAX;
        #pragma unroll
        for (int k = 0; k < F4_PER_STRIPE; ++k) {
            float4 v = src[tid + (k << 8)];
            const int g = (chunk * F4_PER_CHUNK + tid + (k << 8)) << 2;
            if ((unsigned)(bidx - g) < 4u) {
                if      (bidx == g)     v.x = -FLT_MAX;
                else if (bidx == g + 1) v.y = -FLT_MAX;
                else if (bidx == g + 2) v.z = -FLT_MAX;
                else                    v.w = -FLT_MAX;
            }
            a0 = fmaxf(a0, v.x); a1 = fmaxf(a1, v.y);
            a2 = fmaxf(a2, v.z); a3 = fmaxf(a3, v.w);
        }
        mval = fmaxf(fmaxf(a0, a1), fmaxf(a2, a3));
    }

    // block top-3-with-id over the 256 stripe maxima
    float a = mval, b = -FLT_MAX, c = -FLT_MAX;
    int ia = tid, ib = 0, ic = 0;
    for (int off = 32; off >= 1; off >>= 1) {
        float av = __shfl_down(a, off), bv = __shfl_down(b, off), cv = __shfl_down(c, off);
        int   ai = __shfl_down(ia, off), bi = __shfl_down(ib, off), ci = __shfl_down(ic, off);
        ins3i(av, ai, a, b, c, ia, ib, ic);
        ins3i(bv, bi, a, b, c, ia, ib, ic);
        ins3i(cv, ci, a, b, c, ia, ib, ic);
    }
    __shared__ float sv[4][3];
    __shared__ int   si[4][3];
    __shared__ int   top_stripe[3];
    const int lane = tid & 63, wave = tid >> 6;
    if (lane == 0) {
        sv[wave][0] = a;  sv[wave][1] = b;  sv[wave][2] = c;
        si[wave][0] = ia; si[wave][1] = ib; si[wave][2] = ic;
    }
    __syncthreads();
    if (tid == 0) {
        for (int w = 1; w < 4; ++w) {
            ins3i(sv[w][0], si[w][0], a, b, c, ia, ib, ic);
            ins3i(sv[w][1], si[w][1], a, b, c, ia, ib, ic);
            ins3i(sv[w][2], si[w][2], a, b, c, ia, ib, ic);
        }
        top_stripe[0] = ia; top_stripe[1] = ib; top_stripe[2] = ic;
    }
    __syncthreads();

    // rescan the 3 winning stripes (24 float4s, L1/L2-hot), anchor excluded
    __shared__ float trip[24][3];
    if (tid < 24) {
        const int s = top_stripe[tid >> 3];
        const int k = tid & 7;
        const int j = s + (k << 8);
        float4 v = src[j];
        const int g = (chunk * F4_PER_CHUNK + j) << 2;
        if ((unsigned)(bidx - g) < 4u) {
            if      (bidx == g)     v.x = -FLT_MAX;
            else if (bidx == g + 1) v.y = -FLT_MAX;
            else if (bidx == g + 2) v.z = -FLT_MAX;
            else                    v.w = -FLT_MAX;
        }
        float ra = -FLT_MAX, rb = -FLT_MAX, rc = -FLT_MAX;
        ins3(v.x, ra, rb, rc); ins3(v.y, ra, rb, rc);
        ins3(v.z, ra, rb, rc); ins3(v.w, ra, rb, rc);
        trip[tid][0] = ra; trip[tid][1] = rb; trip[tid][2] = rc;
    }
    __syncthreads();
    if (tid == 0) {
        float ra = -FLT_MAX, rb = -FLT_MAX, rc = -FLT_MAX;
        #pragma unroll
        for (int t = 0; t < 24; ++t) {
            ins3(trip[t][0], ra, rb, rc);
            ins3(trip[t][1], ra, rb, rc);
            ins3(trip[t][2], ra, rb, rc);
        }
        float* dst = cand + (size_t)blockIdx.x * 3;
        dst[0] = ra; dst[1] = rb; dst[2] = rc;
    }
}

// ---------------- Kernel 2: merge 48 candidates/row + loss + reduce --------
__global__ __launch_bounds__(128) void k_final(
        const float* __restrict__ cand,
        const float* __restrict__ posval,
        const float* __restrict__ rowreg,
        float*       __restrict__ out) {
    const int r = threadIdx.x;   // one row per thread
    float a = -FLT_MAX, b = -FLT_MAX, c = -FLT_MAX;
    const float* p = cand + (size_t)r * SPLIT * 3;
    #pragma unroll
    for (int k = 0; k < SPLIT * 3; ++k) ins3(p[k], a, b, c);

    float loss = bce(posval[r], 1.0f) + bce(a, 0.0f) + bce(b, 0.0f) + bce(c, 0.0f);
    loss += rowreg[r * CC + 0] + rowreg[r * CC + 1]
          + rowreg[r * CC + 2] + rowreg[r * CC + 3];

    for (int off = 32; off >= 1; off >>= 1) loss += __shfl_down(loss, off);
    __shared__ float sm[2];
    if ((r & 63) == 0) sm[r >> 6] = loss;
    __syncthreads();
    if (r == 0) out[0] = (sm[0] + sm[1]) / (float)(BB * CC);
}

extern "C" void kernel_launch(void* const* d_in, const int* in_sizes, int n_in,
                              void* d_out, int out_size, void* d_ws, size_t ws_size,
                              hipStream_t stream) {
    const float* class_preds = (const float*)d_in[0];
    const float* reg_preds   = (const float*)d_in[1];
    const int*   box_idxs    = (const int*)d_in[2];
    const float* reg_targs   = (const float*)d_in[3];
    float* out = (float*)d_out;

    float* cand   = (float*)d_ws;                       // 6144 floats
    float* posval = cand + (size_t)BB * SPLIT * 3;      // 128 floats
    float* rowreg = posval + BB;                        // 512 floats

    k_chunk_top3<<<BB * SPLIT, 256, 0, stream>>>(class_preds, reg_preds,
                                                 box_idxs, reg_targs,
                                                 cand, posval, rowreg);
    k_final<<<1, 128, 0, stream>>>(cand, posval, rowreg, out);
}

// Round 4
// 20.303 us; speedup vs baseline: 2.1845x; 2.1845x over previous
//
#include <hip/hip_runtime.h>
#include <cfloat>

#define BB    128
#define CC    4
#define NBOXN 131072
#define SPLIT 16                 // chunk-blocks per row
#define F4_PER_CHUNK 2048        // 8192 elems / 4
#define F4_PER_STRIPE 8          // float4s per thread

// branchless sorted-insert into descending triple (a>=b>=c)
__device__ __forceinline__ void ins3(float v, float& a, float& b, float& c) {
    float m1 = fminf(a, v); a = fmaxf(a, v);
    float m2 = fminf(b, m1); b = fmaxf(b, m1);
    c = fmaxf(c, m2);
}

__device__ __forceinline__ float bce(float x, float t) {
    return fmaxf(x, 0.0f) - x * t + log1pf(expf(-fabsf(x)));
}

// ---- Kernel 1: exact per-chunk top-3 via branchless in-stream triples ----
// Each thread keeps a branchless top-3 of its 32 elements (anchor excluded),
// then a 3-value shuffle tree + LDS merge gives the chunk's exact top-3.
// Side jobs (hidden under the stream): chunk-0 blocks gather reg_preds and
// write smooth-L1 partials; one thread stashes the positive logit.
__global__ __launch_bounds__(256) void k_chunk_top3(
        const float* __restrict__ cp,
        const float* __restrict__ rp,
        const int*   __restrict__ box_idxs,
        const float* __restrict__ rt,
        float*       __restrict__ cand,     // [BB*SPLIT*3]
        float*       __restrict__ posval,   // [BB]
        float*       __restrict__ rowreg) { // [BB*CC]
    const int row   = blockIdx.x >> 4;
    const int chunk = blockIdx.x & 15;
    const int tid   = threadIdx.x;
    const int bidx  = box_idxs[row];

    if (chunk == 0) {
        if (tid < CC) {  // scattered reg_preds gathers, latency hidden
            const float pv = rp[((size_t)row * CC + tid) * NBOXN + bidx];
            const float d  = fabsf(pv - rt[row * CC + tid]);
            rowreg[row * CC + tid] = (d < 1.0f) ? 0.5f * d * d : (d - 0.5f);
        } else if (tid == CC) {
            posval[row] = cp[(size_t)row * NBOXN + bidx];
        }
    }

    const float4* src = reinterpret_cast<const float4*>(cp + (size_t)row * NBOXN)
                        + chunk * F4_PER_CHUNK;
    const int gbase = (chunk * F4_PER_CHUNK) << 2;

    float a = -FLT_MAX, b = -FLT_MAX, c = -FLT_MAX;
    #pragma unroll
    for (int k = 0; k < F4_PER_STRIPE; ++k) {
        const int j = tid + (k << 8);
        float4 v = src[j];
        const int g = gbase + (j << 2);
        if ((unsigned)(bidx - g) < 4u) {     // rare, divergent-but-skipped
            if      (bidx == g)     v.x = -FLT_MAX;
            else if (bidx == g + 1) v.y = -FLT_MAX;
            else if (bidx == g + 2) v.z = -FLT_MAX;
            else                    v.w = -FLT_MAX;
        }
        ins3(v.x, a, b, c); ins3(v.y, a, b, c);
        ins3(v.z, a, b, c); ins3(v.w, a, b, c);
    }

    // wave64 shuffle-down tree; lane 0's cone merges disjoint lane sets
    for (int off = 32; off >= 1; off >>= 1) {
        const float a2 = __shfl_down(a, off);
        const float b2 = __shfl_down(b, off);
        const float c2 = __shfl_down(c, off);
        ins3(a2, a, b, c); ins3(b2, a, b, c); ins3(c2, a, b, c);
    }

    __shared__ float sv[4][3];
    const int lane = tid & 63, wave = tid >> 6;
    if (lane == 0) { sv[wave][0] = a; sv[wave][1] = b; sv[wave][2] = c; }
    __syncthreads();
    if (tid == 0) {
        for (int w = 1; w < 4; ++w) {
            ins3(sv[w][0], a, b, c);
            ins3(sv[w][1], a, b, c);
            ins3(sv[w][2], a, b, c);
        }
        float* dst = cand + (size_t)blockIdx.x * 3;
        dst[0] = a; dst[1] = b; dst[2] = c;
    }
}

// ---- Kernel 2: merge 48 exact candidates/row + loss + scalar reduce ----
__global__ __launch_bounds__(128) void k_final(
        const float* __restrict__ cand,
        const float* __restrict__ posval,
        const float* __restrict__ rowreg,
        float*       __restrict__ out) {
    const int r = threadIdx.x;   // one row per thread
    float a = -FLT_MAX, b = -FLT_MAX, c = -FLT_MAX;
    const float* p = cand + (size_t)r * SPLIT * 3;
    #pragma unroll
    for (int k = 0; k < SPLIT * 3; ++k) ins3(p[k], a, b, c);

    float loss = bce(posval[r], 1.0f) + bce(a, 0.0f) + bce(b, 0.0f) + bce(c, 0.0f);
    loss += rowreg[r * CC + 0] + rowreg[r * CC + 1]
          + rowreg[r * CC + 2] + rowreg[r * CC + 3];

    for (int off = 32; off >= 1; off >>= 1) loss += __shfl_down(loss, off);
    __shared__ float sm[2];
    if ((r & 63) == 0) sm[r >> 6] = loss;
    __syncthreads();
    if (r == 0) out[0] = (sm[0] + sm[1]) / (float)(BB * CC);
}

extern "C" void kernel_launch(void* const* d_in, const int* in_sizes, int n_in,
                              void* d_out, int out_size, void* d_ws, size_t ws_size,
                              hipStream_t stream) {
    const float* class_preds = (const float*)d_in[0];
    const float* reg_preds   = (const float*)d_in[1];
    const int*   box_idxs    = (const int*)d_in[2];
    const float* reg_targs   = (const float*)d_in[3];
    float* out = (float*)d_out;

    float* cand   = (float*)d_ws;                   // 6144 floats
    float* posval = cand + (size_t)BB * SPLIT * 3;  // 128 floats
    float* rowreg = posval + BB;                    // 512 floats

    k_chunk_top3<<<BB * SPLIT, 256, 0, stream>>>(class_preds, reg_preds,
                                                 box_idxs, reg_targs,
                                                 cand, posval, rowreg);
    k_final<<<1, 128, 0, stream>>>(cand, posval, rowreg, out);
}